// Round 8
// baseline (36.456 us; speedup 1.0000x reference)
//
#include <hip/hip_runtime.h>
#include <math.h>

#define HH 4
#define DD 64
#define BS 32

__device__ __forceinline__ float silu_f(float x) {
    return x / (1.0f + __expf(-x));
}

// f32 -> bf16 (RNE)
__device__ __forceinline__ unsigned short f2bf(float f) {
    unsigned u = __float_as_uint(f);
    unsigned r = (u + 0x7fffu + ((u >> 16) & 1u)) >> 16;
    return (unsigned short)r;
}
__device__ __forceinline__ float bflo(unsigned w) { return __uint_as_float(w << 16); }
__device__ __forceinline__ float bfhi(unsigned w) { return __uint_as_float(w & 0xffff0000u); }

// Kernel A: per-compressed-block mean of k and v + bf16 copies of k,v.
__global__ __launch_bounds__(256) void hstu_cmp_means(
    const float* __restrict__ k, const float* __restrict__ v,
    const int* __restrict__ offsets, int B,
    float* __restrict__ k_cmp, float* __restrict__ v_cmp,
    unsigned short* __restrict__ kb, unsigned short* __restrict__ vb) {
    int c = blockIdx.x;
    int acc = 0, b = -1, jc = 0;
    for (int bb = 0; bb < B; ++bb) {
        int len = offsets[bb + 1] - offsets[bb];
        int nb = (len + BS - 1) >> 5;
        if (b < 0 && c < acc + nb) { b = bb; jc = c - acc; }
        acc += nb;
    }
    if (b < 0) return;
    int t0 = offsets[b] + jc * BS;
    int cnt = offsets[b + 1] - t0;
    if (cnt > BS) cnt = BS;

    int rg = threadIdx.x >> 6;     // row-group 0..3 (8 rows each)
    int lane = threadIdx.x & 63;   // float4 chunk within the 256-float row

    __shared__ __align__(16) float4 red_k[4][64];
    __shared__ __align__(16) float4 red_v[4][64];

    float4 ks = make_float4(0.f, 0.f, 0.f, 0.f);
    float4 vs = make_float4(0.f, 0.f, 0.f, 0.f);
    #pragma unroll
    for (int m = 0; m < 8; ++m) {
        int i = rg * 8 + m;                 // wave-uniform guard
        if (i < cnt) {
            size_t off = (size_t)(t0 + i) * (HH * DD) + lane * 4;
            const float4 kk = *(const float4*)(k + off);
            const float4 vv = *(const float4*)(v + off);
            ks.x += kk.x; ks.y += kk.y; ks.z += kk.z; ks.w += kk.w;
            vs.x += vv.x; vs.y += vv.y; vs.z += vv.z; vs.w += vv.w;
            ushort4 kh, vh;
            kh.x = f2bf(kk.x); kh.y = f2bf(kk.y); kh.z = f2bf(kk.z); kh.w = f2bf(kk.w);
            vh.x = f2bf(vv.x); vh.y = f2bf(vv.y); vh.z = f2bf(vv.z); vh.w = f2bf(vv.w);
            *(ushort4*)(kb + off) = kh;
            *(ushort4*)(vb + off) = vh;
        }
    }
    red_k[rg][lane] = ks;
    red_v[rg][lane] = vs;
    __syncthreads();
    if (rg == 0) {
        float inv = 1.0f / (float)cnt;
        float4 a = ks, bv = vs;
        #pragma unroll
        for (int g = 1; g < 4; ++g) {
            float4 rk = red_k[g][lane], rv = red_v[g][lane];
            a.x += rk.x; a.y += rk.y; a.z += rk.z; a.w += rk.w;
            bv.x += rv.x; bv.y += rv.y; bv.z += rv.z; bv.w += rv.w;
        }
        a.x *= inv; a.y *= inv; a.z *= inv; a.w *= inv;
        bv.x *= inv; bv.y *= inv; bv.z *= inv; bv.w *= inv;
        *(float4*)(k_cmp + (size_t)c * (HH * DD) + lane * 4) = a;
        *(float4*)(v_cmp + (size_t)c * (HH * DD) + lane * 4) = bv;
    }
}

// Fused B: scores + top-4 + o_cmp + o_slc. grid = T*HH, 4 waves.
// Wave r owns cmp-blocks j = c4*4+r for scoring/o_cmp, and selected block #r for o_slc.
__global__ __launch_bounds__(256) void hstu_fused(
    const float* __restrict__ q,
    const float* __restrict__ g_cmp, const float* __restrict__ g_slc,
    const int* __restrict__ offsets, int B,
    const float* __restrict__ k_cmp, const float* __restrict__ v_cmp,
    const unsigned short* __restrict__ kb, const unsigned short* __restrict__ vb,
    float* __restrict__ o_cmp, float* __restrict__ o_slc) {
    int t = blockIdx.x >> 2, h = blockIdx.x & 3;
    int r = threadIdx.x >> 6;      // wave id 0..3
    int lane = threadIdx.x & 63;

    __shared__ __align__(16) float s_lds[16];
    __shared__ __align__(16) float red_cmp[4][16][4];
    __shared__ __align__(16) float red_slc[4][DD];

    int b = 0;
    while (b + 1 < B && t >= offsets[b + 1]) ++b;
    int seq_start = offsets[b];
    int p = t - seq_start;
    int q_blk = p >> 5;
    int base_cmp = 0, totC = 0;
    for (int bb = 0; bb < B; ++bb) {
        int nb = (offsets[bb + 1] - offsets[bb] + BS - 1) >> 5;
        if (bb < b) base_cmp += nb;
        totC += nb;
    }

    // ---- scores for this wave's 4 blocks: lane=(c4,d4), j = c4*4+r ----
    int d4 = lane & 15, c4 = lane >> 4;
    int j = c4 * 4 + r;
    int ci = base_cmp + j; if (ci > totC - 1) ci = totC - 1;  // safe addr; masked by causal guard
    float4 qf = *(const float4*)(q + ((size_t)t * HH + h) * DD + d4 * 4);
    float4 kk4 = *(const float4*)(k_cmp + (size_t)ci * (HH * DD) + h * DD + d4 * 4);
    float pp = qf.x * kk4.x + qf.y * kk4.y + qf.z * kk4.z + qf.w * kk4.w;
    pp += __shfl_xor(pp, 1);
    pp += __shfl_xor(pp, 2);
    pp += __shfl_xor(pp, 4);
    pp += __shfl_xor(pp, 8);
    float s_sc = pp * 0.125f;
    float p_sc = (j <= q_blk) ? silu_f(s_sc) : 0.f;
    if (d4 == 0) s_lds[j] = s_sc;

    // o_cmp partial: 1 v_cmp load; butterfly over c4
    float4 vv4 = *(const float4*)(v_cmp + (size_t)ci * (HH * DD) + h * DD + d4 * 4);
    float4 facc = make_float4(p_sc * vv4.x, p_sc * vv4.y, p_sc * vv4.z, p_sc * vv4.w);
    facc.x += __shfl_xor(facc.x, 16); facc.x += __shfl_xor(facc.x, 32);
    facc.y += __shfl_xor(facc.y, 16); facc.y += __shfl_xor(facc.y, 32);
    facc.z += __shfl_xor(facc.z, 16); facc.z += __shfl_xor(facc.z, 32);
    facc.w += __shfl_xor(facc.w, 16); facc.w += __shfl_xor(facc.w, 32);
    if (c4 == 0) *(float4*)&red_cmp[r][d4][0] = facc;

    __syncthreads();

    // ---- top-4 via rank + ballot (identical in every wave) ----
    float sc_[16];
    #pragma unroll
    for (int x = 0; x < 4; ++x) {
        float4 sd = ((const float4*)s_lds)[x];
        sc_[x*4+0] = sd.x; sc_[x*4+1] = sd.y; sc_[x*4+2] = sd.z; sc_[x*4+3] = sd.w;
    }
    int j_own = lane >> 2;
    float s_own = sc_[j_own];
    int rank = 0;
    #pragma unroll
    for (int kx = 0; kx < 16; ++kx) {
        bool beats = (kx <= q_blk) && ((sc_[kx] > s_own) || (sc_[kx] == s_own && kx < j_own));
        rank += beats ? 1 : 0;
    }
    bool mine = ((lane & 3) == 0) && (j_own <= q_blk) && (rank < 4);
    unsigned long long msk = __ballot(mine);
    for (int z = 0; z < r; ++z) msk &= msk - 1;   // wave-uniform pop of r bits
    int sel = msk ? (int)(__builtin_ctzll(msk) >> 2) : -1;

    // ---- o_cmp final (wave 0, lanes 0..15) ----
    if (r == 0 && lane < 16) {
        float4 o = *(const float4*)&red_cmp[0][lane][0];
        #pragma unroll
        for (int g = 1; g < 4; ++g) {
            float4 rr = *(const float4*)&red_cmp[g][lane][0];
            o.x += rr.x; o.y += rr.y; o.z += rr.z; o.w += rr.w;
        }
        float gc = g_cmp[(size_t)t * HH + h];
        o.x *= gc; o.y *= gc; o.z *= gc; o.w *= gc;
        *(float4*)(o_cmp + ((size_t)t * HH + h) * DD + lane * 4) = o;
    }

    // ---- o_slc: this wave's selected block, bf16 gather, lane=(it8,d8) ----
    int lim = (sel >= 0) ? min(p - sel * BS + 1, BS) : 0;
    int blk_base = seq_start + sel * BS;
    int d8 = lane & 7, it8 = lane >> 3;
    const float* qbase = q + ((size_t)t * HH + h) * DD + d8 * 8;
    float4 q0 = *(const float4*)qbase;
    float4 q1 = *(const float4*)(qbase + 4);

    uint4 kw[4], vw[4];
    int rows[4];
    #pragma unroll
    for (int m = 0; m < 4; ++m) {
        int i = m * 8 + it8;
        int row = t;
        if (sel >= 0) row = blk_base + min(i, lim - 1);
        rows[m] = row;
        kw[m] = *(const uint4*)(kb + ((size_t)row * HH + h) * DD + d8 * 8);
    }
    #pragma unroll
    for (int m = 0; m < 4; ++m)
        vw[m] = *(const uint4*)(vb + ((size_t)rows[m] * HH + h) * DD + d8 * 8);

    float4 accA = make_float4(0.f, 0.f, 0.f, 0.f);
    float4 accB = make_float4(0.f, 0.f, 0.f, 0.f);
    #pragma unroll
    for (int m = 0; m < 4; ++m) {
        int i = m * 8 + it8;
        float ss = q0.x * bflo(kw[m].x) + q0.y * bfhi(kw[m].x)
                 + q0.z * bflo(kw[m].y) + q0.w * bfhi(kw[m].y)
                 + q1.x * bflo(kw[m].z) + q1.y * bfhi(kw[m].z)
                 + q1.z * bflo(kw[m].w) + q1.w * bfhi(kw[m].w);
        ss += __shfl_xor(ss, 1);
        ss += __shfl_xor(ss, 2);
        ss += __shfl_xor(ss, 4);
        float ps = (i < lim) ? silu_f(ss * 0.125f) : 0.f;
        accA.x += ps * bflo(vw[m].x); accA.y += ps * bfhi(vw[m].x);
        accA.z += ps * bflo(vw[m].y); accA.w += ps * bfhi(vw[m].y);
        accB.x += ps * bflo(vw[m].z); accB.y += ps * bfhi(vw[m].z);
        accB.z += ps * bflo(vw[m].w); accB.w += ps * bfhi(vw[m].w);
    }
    accA.x += __shfl_xor(accA.x, 8); accA.x += __shfl_xor(accA.x, 16); accA.x += __shfl_xor(accA.x, 32);
    accA.y += __shfl_xor(accA.y, 8); accA.y += __shfl_xor(accA.y, 16); accA.y += __shfl_xor(accA.y, 32);
    accA.z += __shfl_xor(accA.z, 8); accA.z += __shfl_xor(accA.z, 16); accA.z += __shfl_xor(accA.z, 32);
    accA.w += __shfl_xor(accA.w, 8); accA.w += __shfl_xor(accA.w, 16); accA.w += __shfl_xor(accA.w, 32);
    accB.x += __shfl_xor(accB.x, 8); accB.x += __shfl_xor(accB.x, 16); accB.x += __shfl_xor(accB.x, 32);
    accB.y += __shfl_xor(accB.y, 8); accB.y += __shfl_xor(accB.y, 16); accB.y += __shfl_xor(accB.y, 32);
    accB.z += __shfl_xor(accB.z, 8); accB.z += __shfl_xor(accB.z, 16); accB.z += __shfl_xor(accB.z, 32);
    accB.w += __shfl_xor(accB.w, 8); accB.w += __shfl_xor(accB.w, 16); accB.w += __shfl_xor(accB.w, 32);

    if (r != 0 && it8 == 0) {
        *(float4*)&red_slc[r][d8 * 8]     = accA;
        *(float4*)&red_slc[r][d8 * 8 + 4] = accB;
    }
    __syncthreads();
    if (r == 0 && it8 == 0) {
        #pragma unroll
        for (int g = 1; g < 4; ++g) {
            float4 ra = *(const float4*)&red_slc[g][d8 * 8];
            float4 rb = *(const float4*)&red_slc[g][d8 * 8 + 4];
            accA.x += ra.x; accA.y += ra.y; accA.z += ra.z; accA.w += ra.w;
            accB.x += rb.x; accB.y += rb.y; accB.z += rb.z; accB.w += rb.w;
        }
        float gs = g_slc[(size_t)t * HH + h];
        accA.x *= gs; accA.y *= gs; accA.z *= gs; accA.w *= gs;
        accB.x *= gs; accB.y *= gs; accB.z *= gs; accB.w *= gs;
        float* ob = o_slc + ((size_t)t * HH + h) * DD + d8 * 8;
        *(float4*)ob = accA;
        *(float4*)(ob + 4) = accB;
    }
}

extern "C" void kernel_launch(void* const* d_in, const int* in_sizes, int n_in,
                              void* d_out, int out_size, void* d_ws, size_t ws_size,
                              hipStream_t stream) {
    const float* q     = (const float*)d_in[0];
    const float* k     = (const float*)d_in[1];
    const float* v     = (const float*)d_in[2];
    const float* g_cmp = (const float*)d_in[3];
    const float* g_slc = (const float*)d_in[4];
    const int*   offs  = (const int*)d_in[5];

    int T = in_sizes[0] / (HH * DD);
    int B = in_sizes[5] - 1;
    int maxC = (T + BS - 1) / BS + B;

    float* k_cmp = (float*)d_ws;
    float* v_cmp = k_cmp + (size_t)maxC * HH * DD;
    unsigned short* kb = (unsigned short*)(v_cmp + (size_t)maxC * HH * DD);
    unsigned short* vb = kb + (size_t)T * HH * DD;
    float* o_cmp = (float*)d_out;
    float* o_slc = (float*)d_out + (size_t)T * HH * DD;

    hipLaunchKernelGGL(hstu_cmp_means, dim3(maxC), dim3(256), 0, stream,
                       k, v, offs, B, k_cmp, v_cmp, kb, vb);
    hipLaunchKernelGGL(hstu_fused, dim3(T * HH), dim3(256), 0, stream,
                       q, g_cmp, g_slc, offs, B, k_cmp, v_cmp, kb, vb, o_cmp, o_slc);
}